// Round 17
// baseline (25.899 us; speedup 1.0000x reference)
//
#include <hip/hip_runtime.h>
#include <math.h>

#define DEV_INLINE __device__ __forceinline__

typedef float v2f __attribute__((ext_vector_type(2)));

constexpr int DIM = 8;
constexpr int TRI = 36;      // 8*9/2
#define EPSF 1e-10f

DEV_INLINE constexpr int SI(int i, int j) { return i * (i + 1) / 2 + j; } // i >= j
#define SA(a, i, j) ((i) >= (j) ? (a)[SI((i),(j))] : (a)[SI((j),(i))])

DEV_INLINE v2f sp2(float s) { return (v2f){s, s}; }

// element (i,j) of full symmetric matrix stored as 8 rows x 4 float2 pairs
#define EL(A, i, j) (A[i][(j) >> 1][(j) & 1])

// ---- DPP quad_perm add: x += x_from(lane ^ m) within each lane-quad ----
// CTRL: xor1 = quad_perm[1,0,3,2] -> 177; xor2 = quad_perm[2,3,0,1] -> 78.
template <int CTRL>
DEV_INLINE float dpp_add(float x) {
  int xi = __builtin_bit_cast(int, x);
  int sh = __builtin_amdgcn_update_dpp(0, xi, CTRL, 0xf, 0xf, true);
  return x + __builtin_bit_cast(float, sh);
}

// fill elements (i,j), j > (i|1), from (j,i)
DEV_INLINE void mirror(v2f C[DIM][4]) {
  #pragma unroll
  for (int i = 0; i < DIM; ++i)
    #pragma unroll
    for (int j = (i | 1) + 1; j < DIM; ++j)
      EL(C, i, j) = EL(C, j, i);
}

// C = A*B for commuting symmetric A,B (result symmetric): lower pairs + mirror
DEV_INLINE void mm_sym(v2f C[DIM][4], const v2f A[DIM][4], const v2f B[DIM][4]) {
  #pragma unroll
  for (int i = 0; i < DIM; ++i) {
    #pragma unroll
    for (int j2 = 0; j2 <= (i >> 1); ++j2) {
      v2f acc = sp2(0.f);
      #pragma unroll
      for (int k = 0; k < DIM; ++k)
        acc = __builtin_elementwise_fma(sp2(EL(A, i, k)), B[k][j2], acc);
      C[i][j2] = acc;
    }
  }
  mirror(C);
}

// M = 1.875 I - 1.25 W + 0.375 W2   (order-3 NS polynomial)
DEV_INLINE void mk_m3(v2f M[DIM][4], const v2f W[DIM][4], const v2f W2[DIM][4]) {
  #pragma unroll
  for (int i = 0; i < DIM; ++i) {
    #pragma unroll
    for (int j2 = 0; j2 <= (i >> 1); ++j2)
      M[i][j2] = __builtin_elementwise_fma(W2[i][j2], sp2(0.375f),
                                           W[i][j2] * sp2(-1.25f));
    EL(M, i, i) += 1.875f;
  }
  mirror(M);
}

// one cubic coupled-NS application: (Yi,Zi) -> (Yo,Zo), e' = 0.625 e^3
DEV_INLINE void cubic_step(v2f Yo[DIM][4], v2f Zo[DIM][4],
                           const v2f Yi[DIM][4], const v2f Zi[DIM][4]) {
  v2f W[DIM][4], W2[DIM][4], M[DIM][4];
  mm_sym(W, Zi, Yi);
  mm_sym(W2, W, W);
  mk_m3(M, W, W2);
  mm_sym(Yo, Yi, M);
  mm_sym(Zo, M, Zi);
}

// Load embedding row idx into lower-tri p with diag clamped >= 1e-4.
DEV_INLINE void load_L(const float* __restrict__ emb, int idx, float p[TRI]) {
  const float4* row = reinterpret_cast<const float4*>(emb + (size_t)idx * TRI);
  #pragma unroll
  for (int q = 0; q < 9; ++q) {
    float4 v = row[q];
    p[4 * q + 0] = v.x; p[4 * q + 1] = v.y; p[4 * q + 2] = v.z; p[4 * q + 3] = v.w;
  }
  #pragma unroll
  for (int i = 0; i < DIM; ++i) p[SI(i, i)] = fmaxf(p[SI(i, i)], 1e-4f);
}

// token density contribution from preloaded factor p: acc += (L L^T)/tr * mask
DEV_INLINE void accum_tok(const float p[TRI], float mask, float acc[TRI],
                          float& msum) {
  float r[TRI];
  float tr = 0.f;
  #pragma unroll
  for (int i = 0; i < DIM; ++i) {
    #pragma unroll
    for (int j = 0; j <= i; ++j) {
      float s = 0.f;
      #pragma unroll
      for (int k = 0; k <= j; ++k) s = fmaf(p[SI(i, k)], p[SI(j, k)], s);
      if (i == j) { s += EPSF; tr += s; }
      r[SI(i, j)] = s;
    }
  }
  float w = mask * __builtin_amdgcn_rcpf(tr + EPSF);
  #pragma unroll
  for (int u = 0; u < TRI; ++u) acc[u] = fmaf(r[u], w, acc[u]);
  msum += mask;
}

__global__ void __launch_bounds__(256, 1)
qcbow_main(const int* __restrict__ contexts, const int* __restrict__ targets,
           const float* __restrict__ emb, float* __restrict__ out,
           int B, float invB) {
  const int tid = threadIdx.x;                 // 256 threads = 4 waves
  const int r = tid & 3, sl = tid >> 2;        // 4 lanes/sample, 64 samples/block
  int sample = blockIdx.x * 64 + sl;
  const float ok = (sample < B) ? 1.f : 0.f;
  if (sample >= B) sample = B - 1;

  // ---- gather phase: lane r owns tokens {r, r+4, 8+r|r<2}; all prefetch ----
  const int* crow = contexts + (size_t)sample * 10;
  int i1 = crow[r];
  int i2 = crow[4 + r];
  int i3 = (r < 2) ? crow[8 + r] : 0;  // dummy lanes share row 0 (one cacheline)
  float m1 = (i1 != 0) ? 1.f : 0.f;
  float m2 = (i2 != 0) ? 1.f : 0.f;
  float m3 = (r < 2 && i3 != 0) ? 1.f : 0.f;

  float p1[TRI], p2[TRI], p3[TRI], Tl[TRI];
  load_L(emb, i1, p1);                 // 4 independent gathers in flight
  load_L(emb, i2, p2);
  load_L(emb, i3, p3);
  load_L(emb, targets[sample], Tl);    // same addr across the 4 lanes -> merged

  // ---- partial context-average density ----
  float acc[TRI];
  #pragma unroll
  for (int u = 0; u < TRI; ++u) acc[u] = 0.f;
  float msum = 0.f;
  accum_tok(p1, m1, acc, msum);
  accum_tok(p2, m2, acc, msum);
  accum_tok(p3, m3, acc, msum);

  // ---- width-4 butterfly via DPP quad_perm (no LDS, no lgkm waits) ----
  #pragma unroll
  for (int u = 0; u < TRI; ++u) acc[u] = dpp_add<177>(acc[u]);  // xor 1
  msum = dpp_add<177>(msum);
  #pragma unroll
  for (int u = 0; u < TRI; ++u) acc[u] = dpp_add<78>(acc[u]);   // xor 2
  msum = dpp_add<78>(msum);
  float rinv = __builtin_amdgcn_rcpf(msum + EPSF);

  // ---- tr(sigma_unnorm)+EPS ----
  float trt = 8.f * EPSF + EPSF;
  #pragma unroll
  for (int u = 0; u < TRI; ++u) trt = fmaf(Tl[u], Tl[u], trt);

  // ---- A = T^T rho T, built row-by-row (redundant per lane, free @1 wave/SIMD) ----
  float Al[TRI];
  float trA = 0.f;
  #pragma unroll
  for (int rr = 0; rr < DIM; ++rr) {
    v2f Wr[4];
    #pragma unroll
    for (int m2q = 0; m2q < 4; ++m2q) Wr[m2q] = sp2(0.f);
    #pragma unroll
    for (int k = rr; k < DIM; ++k) {
      float tkr = Tl[SI(k, rr)];
      #pragma unroll
      for (int m2q = 0; m2q < 4; ++m2q) {
        v2f rk = (v2f){SA(acc, k, 2 * m2q), SA(acc, k, 2 * m2q + 1)};
        Wr[m2q] = __builtin_elementwise_fma(sp2(tkr), rk, Wr[m2q]);
      }
    }
    #pragma unroll
    for (int j = 0; j <= rr; ++j) {
      float s = 0.f;
      #pragma unroll
      for (int k = j; k < DIM; ++k) s = fmaf(Wr[k >> 1][k & 1], Tl[SI(k, j)], s);
      Al[SI(rr, j)] = s;
      if (j == rr) trA += s;
    }
  }

  // ---- spectral scaling S = tr(A^2)/tr(A) ----
  float t2 = 0.f;
  #pragma unroll
  for (int rr = 0; rr < DIM; ++rr) {
    #pragma unroll
    for (int j = 0; j <= rr; ++j) {
      float a = Al[SI(rr, j)];
      t2 = fmaf((rr == j) ? a : 2.f * a, a, t2);
    }
  }
  float Sc = t2 * __builtin_amdgcn_rcpf(trA + 1e-30f);
  float iS = trA * __builtin_amdgcn_rcpf(t2 + 1e-30f);

  // ---- Y0 = A * iS (pair storage) ----
  v2f Y[DIM][4], Z[DIM][4], Yt[DIM][4], Zt[DIM][4];
  #pragma unroll
  for (int rr = 0; rr < DIM; ++rr)
    #pragma unroll
    for (int j2 = 0; j2 <= (rr >> 1); ++j2)
      Y[rr][j2] = (v2f){SA(Al, rr, 2 * j2), SA(Al, rr, 2 * j2 + 1)} * sp2(iS);
  mirror(Y);

  // ---- app 1 (quadratic, peeled; Z0 = I) ----
  #pragma unroll
  for (int rr = 0; rr < DIM; ++rr) {
    #pragma unroll
    for (int j2 = 0; j2 <= (rr >> 1); ++j2) Z[rr][j2] = Y[rr][j2] * sp2(-0.5f);
    EL(Z, rr, rr) += 1.5f;
  }
  mirror(Z);
  mm_sym(Yt, Y, Z);                // (Yt, Z) = (Y1, Z1)

  // ---- apps 2,3 (cubic) ----
  cubic_step(Y, Zt, Yt, Z);        // (Y, Zt) = (Y2, Z2)
  cubic_step(Yt, Z, Y, Zt);        // (Yt, Z) = (Y3, Z3)

  // ---- app 4 (cubic, fused): trY = <Y3, M4>_F ----
  float trY;
  {
    v2f W[DIM][4], W2[DIM][4], M[DIM][4];
    mm_sym(W, Z, Yt);
    mm_sym(W2, W, W);
    mk_m3(M, W, W2);
    v2f d = sp2(0.f);
    #pragma unroll
    for (int rr = 0; rr < DIM; ++rr)
      #pragma unroll
      for (int j2 = 0; j2 < 4; ++j2)
        d = __builtin_elementwise_fma(Yt[rr][j2], M[rr][j2], d);
    trY = d.x + d.y;
  }

  // ---- f = S * trY^2 * rinv / trt ----
  float f = Sc * trY * trY * rinv * __builtin_amdgcn_rcpf(trt);
  f = fminf(fmaxf(f, 0.f), 1.f);
  float loss = -logf(fmaxf(f, 1e-8f)) + 0.1f * (1.f - f);

  // ---- per-wave reduce, 4 wave-partials -> 1 block partial, 1 atomic ----
  float val = (r == 0) ? ok * loss * invB : 0.f;
  #pragma unroll
  for (int off = 32; off > 0; off >>= 1) val += __shfl_down(val, off);
  __shared__ float wpart[4];
  if ((tid & 63) == 0) wpart[tid >> 6] = val;
  __syncthreads();
  if (tid == 0)
    atomicAdd(out, (wpart[0] + wpart[1]) + (wpart[2] + wpart[3]));
}

extern "C" void kernel_launch(void* const* d_in, const int* in_sizes, int n_in,
                              void* d_out, int out_size, void* d_ws, size_t ws_size,
                              hipStream_t stream) {
  const int* contexts = (const int*)d_in[0];
  const int* targets  = (const int*)d_in[1];
  const float* emb    = (const float*)d_in[2];
  float* out = (float*)d_out;
  const int B = in_sizes[1];

  hipMemsetAsync(out, 0, sizeof(float), stream);  // zero the accumulator
  const int grid = (B + 63) / 64;      // 4 lanes/sample, 64 samples/block (4 waves)
  qcbow_main<<<grid, 256, 0, stream>>>(contexts, targets, emb, out, B, 1.0f / (float)B);
}

// Round 18
// 19.982 us; speedup vs baseline: 1.2961x; 1.2961x over previous
//
#include <hip/hip_runtime.h>
#include <math.h>

#define DEV_INLINE __device__ __forceinline__

typedef float v2f __attribute__((ext_vector_type(2)));

constexpr int DIM = 8;
constexpr int TRI = 36;      // 8*9/2
#define EPSF 1e-10f

DEV_INLINE constexpr int SI(int i, int j) { return i * (i + 1) / 2 + j; } // i >= j
#define SA(a, i, j) ((i) >= (j) ? (a)[SI((i),(j))] : (a)[SI((j),(i))])

DEV_INLINE v2f sp2(float s) { return (v2f){s, s}; }

// element (i,j) of full symmetric matrix stored as 8 rows x 4 float2 pairs
#define EL(A, i, j) (A[i][(j) >> 1][(j) & 1])

// ---- DPP quad_perm add: x += x_from(lane ^ m) within each lane-quad ----
// CTRL: xor1 = quad_perm[1,0,3,2] -> 177; xor2 = quad_perm[2,3,0,1] -> 78.
template <int CTRL>
DEV_INLINE float dpp_add(float x) {
  int xi = __builtin_bit_cast(int, x);
  int sh = __builtin_amdgcn_update_dpp(0, xi, CTRL, 0xf, 0xf, true);
  return x + __builtin_bit_cast(float, sh);
}

// fill elements (i,j), j > (i|1), from (j,i)
DEV_INLINE void mirror(v2f C[DIM][4]) {
  #pragma unroll
  for (int i = 0; i < DIM; ++i)
    #pragma unroll
    for (int j = (i | 1) + 1; j < DIM; ++j)
      EL(C, i, j) = EL(C, j, i);
}

// C = A*B for commuting symmetric A,B (result symmetric): lower pairs + mirror
DEV_INLINE void mm_sym(v2f C[DIM][4], const v2f A[DIM][4], const v2f B[DIM][4]) {
  #pragma unroll
  for (int i = 0; i < DIM; ++i) {
    #pragma unroll
    for (int j2 = 0; j2 <= (i >> 1); ++j2) {
      v2f acc = sp2(0.f);
      #pragma unroll
      for (int k = 0; k < DIM; ++k)
        acc = __builtin_elementwise_fma(sp2(EL(A, i, k)), B[k][j2], acc);
      C[i][j2] = acc;
    }
  }
  mirror(C);
}

// M = 1.875 I - 1.25 W + 0.375 W2   (order-3 NS polynomial)
DEV_INLINE void mk_m3(v2f M[DIM][4], const v2f W[DIM][4], const v2f W2[DIM][4]) {
  #pragma unroll
  for (int i = 0; i < DIM; ++i) {
    #pragma unroll
    for (int j2 = 0; j2 <= (i >> 1); ++j2)
      M[i][j2] = __builtin_elementwise_fma(W2[i][j2], sp2(0.375f),
                                           W[i][j2] * sp2(-1.25f));
    EL(M, i, i) += 1.875f;
  }
  mirror(M);
}

// one cubic coupled-NS application: (Yi,Zi) -> (Yo,Zo), e' = 0.625 e^3
DEV_INLINE void cubic_step(v2f Yo[DIM][4], v2f Zo[DIM][4],
                           const v2f Yi[DIM][4], const v2f Zi[DIM][4]) {
  v2f W[DIM][4], W2[DIM][4], M[DIM][4];
  mm_sym(W, Zi, Yi);
  mm_sym(W2, W, W);
  mk_m3(M, W, W2);
  mm_sym(Yo, Yi, M);
  mm_sym(Zo, M, Zi);
}

// Load embedding row idx into lower-tri p with diag clamped >= 1e-4.
DEV_INLINE void load_L(const float* __restrict__ emb, int idx, float p[TRI]) {
  const float4* row = reinterpret_cast<const float4*>(emb + (size_t)idx * TRI);
  #pragma unroll
  for (int q = 0; q < 9; ++q) {
    float4 v = row[q];
    p[4 * q + 0] = v.x; p[4 * q + 1] = v.y; p[4 * q + 2] = v.z; p[4 * q + 3] = v.w;
  }
  #pragma unroll
  for (int i = 0; i < DIM; ++i) p[SI(i, i)] = fmaxf(p[SI(i, i)], 1e-4f);
}

// token density contribution from preloaded factor p: acc += (L L^T)/tr * mask
DEV_INLINE void accum_tok(const float p[TRI], float mask, float acc[TRI],
                          float& msum) {
  float r[TRI];
  float tr = 0.f;
  #pragma unroll
  for (int i = 0; i < DIM; ++i) {
    #pragma unroll
    for (int j = 0; j <= i; ++j) {
      float s = 0.f;
      #pragma unroll
      for (int k = 0; k <= j; ++k) s = fmaf(p[SI(i, k)], p[SI(j, k)], s);
      if (i == j) { s += EPSF; tr += s; }
      r[SI(i, j)] = s;
    }
  }
  float w = mask * __builtin_amdgcn_rcpf(tr + EPSF);
  #pragma unroll
  for (int u = 0; u < TRI; ++u) acc[u] = fmaf(r[u], w, acc[u]);
  msum += mask;
}

__global__ void __launch_bounds__(64, 1)
qcbow_main(const int* __restrict__ contexts, const int* __restrict__ targets,
           const float* __restrict__ emb, float* __restrict__ ws,
           int B, float invB) {
  const int tid = threadIdx.x;
  const int r = tid & 3, sl = tid >> 2;        // 4 lanes per sample, 16 samples/wave
  int sample = blockIdx.x * 16 + sl;
  const float ok = (sample < B) ? 1.f : 0.f;
  if (sample >= B) sample = B - 1;

  // ---- gather phase: lane r owns tokens {r, r+4, 8+r|r<2}; all prefetch ----
  const int* crow = contexts + (size_t)sample * 10;
  int i1 = crow[r];
  int i2 = crow[4 + r];
  int i3 = (r < 2) ? crow[8 + r] : 0;  // dummy lanes share row 0 (one cacheline)
  float m1 = (i1 != 0) ? 1.f : 0.f;
  float m2 = (i2 != 0) ? 1.f : 0.f;
  float m3 = (r < 2 && i3 != 0) ? 1.f : 0.f;

  float p1[TRI], p2[TRI], p3[TRI], Tl[TRI];
  load_L(emb, i1, p1);                 // 4 independent gathers in flight
  load_L(emb, i2, p2);
  load_L(emb, i3, p3);
  load_L(emb, targets[sample], Tl);    // same addr across the 4 lanes -> merged

  // ---- partial context-average density ----
  float acc[TRI];
  #pragma unroll
  for (int u = 0; u < TRI; ++u) acc[u] = 0.f;
  float msum = 0.f;
  accum_tok(p1, m1, acc, msum);
  accum_tok(p2, m2, acc, msum);
  accum_tok(p3, m3, acc, msum);

  // ---- width-4 butterfly via DPP quad_perm (no LDS, no lgkm waits) ----
  #pragma unroll
  for (int u = 0; u < TRI; ++u) acc[u] = dpp_add<177>(acc[u]);  // xor 1
  msum = dpp_add<177>(msum);
  #pragma unroll
  for (int u = 0; u < TRI; ++u) acc[u] = dpp_add<78>(acc[u]);   // xor 2
  msum = dpp_add<78>(msum);
  float rinv = __builtin_amdgcn_rcpf(msum + EPSF);

  // ---- tr(sigma_unnorm)+EPS ----
  float trt = 8.f * EPSF + EPSF;
  #pragma unroll
  for (int u = 0; u < TRI; ++u) trt = fmaf(Tl[u], Tl[u], trt);

  // ---- A = T^T rho T, built row-by-row (redundant per lane, free @1 wave/SIMD) ----
  float Al[TRI];
  float trA = 0.f;
  #pragma unroll
  for (int rr = 0; rr < DIM; ++rr) {
    v2f Wr[4];
    #pragma unroll
    for (int m2q = 0; m2q < 4; ++m2q) Wr[m2q] = sp2(0.f);
    #pragma unroll
    for (int k = rr; k < DIM; ++k) {
      float tkr = Tl[SI(k, rr)];
      #pragma unroll
      for (int m2q = 0; m2q < 4; ++m2q) {
        v2f rk = (v2f){SA(acc, k, 2 * m2q), SA(acc, k, 2 * m2q + 1)};
        Wr[m2q] = __builtin_elementwise_fma(sp2(tkr), rk, Wr[m2q]);
      }
    }
    #pragma unroll
    for (int j = 0; j <= rr; ++j) {
      float s = 0.f;
      #pragma unroll
      for (int k = j; k < DIM; ++k) s = fmaf(Wr[k >> 1][k & 1], Tl[SI(k, j)], s);
      Al[SI(rr, j)] = s;
      if (j == rr) trA += s;
    }
  }

  // ---- spectral scaling S = tr(A^2)/tr(A) ----
  float t2 = 0.f;
  #pragma unroll
  for (int rr = 0; rr < DIM; ++rr) {
    #pragma unroll
    for (int j = 0; j <= rr; ++j) {
      float a = Al[SI(rr, j)];
      t2 = fmaf((rr == j) ? a : 2.f * a, a, t2);
    }
  }
  float Sc = t2 * __builtin_amdgcn_rcpf(trA + 1e-30f);
  float iS = trA * __builtin_amdgcn_rcpf(t2 + 1e-30f);

  // ---- Y0 = A * iS (pair storage) ----
  v2f Y[DIM][4], Z[DIM][4], Yt[DIM][4], Zt[DIM][4];
  #pragma unroll
  for (int rr = 0; rr < DIM; ++rr)
    #pragma unroll
    for (int j2 = 0; j2 <= (rr >> 1); ++j2)
      Y[rr][j2] = (v2f){SA(Al, rr, 2 * j2), SA(Al, rr, 2 * j2 + 1)} * sp2(iS);
  mirror(Y);

  // ---- app 1 (quadratic, peeled; Z0 = I) ----
  #pragma unroll
  for (int rr = 0; rr < DIM; ++rr) {
    #pragma unroll
    for (int j2 = 0; j2 <= (rr >> 1); ++j2) Z[rr][j2] = Y[rr][j2] * sp2(-0.5f);
    EL(Z, rr, rr) += 1.5f;
  }
  mirror(Z);
  mm_sym(Yt, Y, Z);                // (Yt, Z) = (Y1, Z1)

  // ---- apps 2,3 (cubic) ----
  cubic_step(Y, Zt, Yt, Z);        // (Y, Zt) = (Y2, Z2)
  cubic_step(Yt, Z, Y, Zt);        // (Yt, Z) = (Y3, Z3)

  // ---- app 4 (cubic, fused): trY = <Y3, M4>_F ----
  float trY;
  {
    v2f W[DIM][4], W2[DIM][4], M[DIM][4];
    mm_sym(W, Z, Yt);
    mm_sym(W2, W, W);
    mk_m3(M, W, W2);
    v2f d = sp2(0.f);
    #pragma unroll
    for (int rr = 0; rr < DIM; ++rr)
      #pragma unroll
      for (int j2 = 0; j2 < 4; ++j2)
        d = __builtin_elementwise_fma(Yt[rr][j2], M[rr][j2], d);
    trY = d.x + d.y;
  }

  // ---- f = S * trY^2 * rinv / trt ----
  float f = Sc * trY * trY * rinv * __builtin_amdgcn_rcpf(trt);
  f = fminf(fmaxf(f, 0.f), 1.f);
  float loss = -logf(fmaxf(f, 1e-8f)) + 0.1f * (1.f - f);

  // ---- per-block partial (no atomics): only lane r==0 of each sample counts ----
  float val = (r == 0) ? ok * loss * invB : 0.f;
  #pragma unroll
  for (int off = 32; off > 0; off >>= 1) val += __shfl_down(val, off);
  if (tid == 0) ws[blockIdx.x] = val;
}

__global__ void __launch_bounds__(256, 1)
qcbow_reduce(const float* __restrict__ ws, float* __restrict__ out, int n) {
  const int tid = threadIdx.x;            // 256 threads = 4 waves
  const float4* w4 = (const float4*)ws;
  const int n4 = n >> 2;
  float4 s = make_float4(0.f, 0.f, 0.f, 0.f);
  for (int i = tid; i < n4; i += 256) {   // n=1024 -> exactly 1 float4/thread
    float4 v = w4[i];
    s.x += v.x; s.y += v.y; s.z += v.z; s.w += v.w;
  }
  if (tid == 0) {                          // scalar remainder (n % 4)
    for (int i = n & ~3; i < n; ++i) s.x += ws[i];
  }
  float v = (s.x + s.y) + (s.z + s.w);
  #pragma unroll
  for (int off = 32; off > 0; off >>= 1) v += __shfl_down(v, off);
  __shared__ float red[4];
  if ((tid & 63) == 0) red[tid >> 6] = v;
  __syncthreads();
  if (tid == 0) out[0] = (red[0] + red[1]) + (red[2] + red[3]);
}

extern "C" void kernel_launch(void* const* d_in, const int* in_sizes, int n_in,
                              void* d_out, int out_size, void* d_ws, size_t ws_size,
                              hipStream_t stream) {
  const int* contexts = (const int*)d_in[0];
  const int* targets  = (const int*)d_in[1];
  const float* emb    = (const float*)d_in[2];
  float* out = (float*)d_out;
  float* ws  = (float*)d_ws;
  const int B = in_sizes[1];

  const int grid = (B + 15) / 16;       // 4 lanes/sample, 16 samples/wave
  qcbow_main<<<grid, 64, 0, stream>>>(contexts, targets, emb, ws, B, 1.0f / (float)B);
  qcbow_reduce<<<1, 256, 0, stream>>>(ws, out, grid);
}